// Round 1
// 258.885 us; speedup vs baseline: 1.0787x; 1.0787x over previous
//
#include <hip/hip_runtime.h>
#include <math.h>

#define NN 100000
#define NE 1600000
#define F_IN 128
#define HEADS 4
#define HC 128
#define NEG_SLOPE 0.2f
#define NBKT 391    // buckets of 256 dst nodes: (NN+255)/256
#define BCAP 5120   // bucket capacity (mean 4096, sigma 64 -> +16 sigma)
#define LDK 136     // padded LDS row (bf16): 128 + 8 -> 2-way bank alias (free)
#define NSTRIP 6250 // NN/16

typedef __attribute__((ext_vector_type(8))) short bf16x8;
typedef __attribute__((ext_vector_type(4))) float f32x4;

static __device__ __forceinline__ short f2bf_rne(float f) {
    unsigned u = __float_as_uint(f);
    unsigned r = (u + 0x7FFFu + ((u >> 16) & 1u)) >> 16;
    return (short)r;
}
static __device__ __forceinline__ float bf2f(short s) {
    return __uint_as_float(((unsigned)(unsigned short)s) << 16);
}

// ---------------------------------------------------------------------------
// Kernel 1: W prep (transpose + bf16 hi/lo split) + int64/int32 detect (blk 0)
// + bcur zero (blks 1,2).
__global__ __launch_bounds__(256) void prep_kernel(
        const float* __restrict__ W, short* __restrict__ wt_hi, short* __restrict__ wt_lo,
        const int* __restrict__ ei, int* __restrict__ flag, int* __restrict__ bcur) {
    if (blockIdx.x == 0 && threadIdx.x < 64) {
        int l = threadIdx.x;
        int v = ei[2 * l + 1];
        for (int off = 1; off < 64; off <<= 1) v |= __shfl_xor(v, off);
        if (l == 0) *flag = (v == 0) ? 1 : 0;   // 1 => int64 layout
    }
    if (blockIdx.x == 1 || blockIdx.x == 2) {
        int z = (blockIdx.x - 1) * 256 + threadIdx.x;
        if (z < NBKT) bcur[z] = 0;
    }
    int i = blockIdx.x * 256 + threadIdx.x;
    if (i >= F_IN * HC) return;
    int k = i >> 7, n = i & 127;
    float f = W[k * HC + n];
    short hb = f2bf_rne(f);
    wt_hi[n * F_IN + k] = hb;
    wt_lo[n * F_IN + k] = f2bf_rne(f - bf2f(hb));
}

// ---------------------------------------------------------------------------
// Kernel 2: h = x @ W via split-bf16 MFMA, W-half staged in LDS.
// Block = 4 waves = 64 rows x 128 cols. The block processes column half 0,
// re-stages LDS with half 1, and reuses the A-fragments kept in registers --
// so x (51.2 MB) is read and converted exactly ONCE (was twice).
__global__ __launch_bounds__(256, 4) void mfma_gemm_kernel(
        const float* __restrict__ x, const short* __restrict__ wt_hi,
        const short* __restrict__ wt_lo, const float* __restrict__ att_src,
        const float* __restrict__ att_dst, unsigned short* __restrict__ h_bf,
        float* __restrict__ a_src, float* __restrict__ a_dst) {
    __shared__ short lw_hi[64 * LDK];   // 17 KB
    __shared__ short lw_lo[64 * LDK];   // 17 KB
    int t = threadIdx.x;
    int blk = blockIdx.x;

    // stage W cols 0-63: 2 x 16 KB, 16B chunks; chunk c -> row c/16, cols (c%16)*8
    for (int c = t; c < 1024; c += 256) {
        int n = c >> 4;
        int kk = (c & 15) * 8;
        *(bf16x8*)(lw_hi + n * LDK + kk) = *(const bf16x8*)(wt_hi + n * F_IN + kk);
        *(bf16x8*)(lw_lo + n * LDK + kk) = *(const bf16x8*)(wt_lo + n * F_IN + kk);
    }
    __syncthreads();

    int strip = blk * 4 + (t >> 6);
    int valid = strip < NSTRIP;
    int sclamp = valid ? strip : NSTRIP - 1;   // clamp: keep all waves alive for barriers
    int lane = t & 63;
    int l15 = lane & 15;
    int q = lane >> 4;

    f32x4 acc[8];
#pragma unroll
    for (int nt = 0; nt < 8; ++nt) acc[nt] = (f32x4){0.f, 0.f, 0.f, 0.f};

    bf16x8 ah[4], al[4];
    const float* xp = x + (size_t)(sclamp * 16 + l15) * F_IN + q * 8;

    // phase 1: load+convert x fragments (kept in regs), MFMA cols 0-63
#pragma unroll
    for (int ki = 0; ki < 4; ++ki) {
        float4 v0 = *(const float4*)(xp + ki * 32);
        float4 v1 = *(const float4*)(xp + ki * 32 + 4);
        float vv[8] = {v0.x, v0.y, v0.z, v0.w, v1.x, v1.y, v1.z, v1.w};
#pragma unroll
        for (int j = 0; j < 8; ++j) {
            short hb = f2bf_rne(vv[j]);
            ah[ki][j] = hb;
            al[ki][j] = f2bf_rne(vv[j] - bf2f(hb));
        }
        int koff = ki * 32 + q * 8;
#pragma unroll
        for (int nt = 0; nt < 4; ++nt) {
            int lidx = (nt * 16 + l15) * LDK + koff;
            bf16x8 b_hi = *(const bf16x8*)(lw_hi + lidx);
            bf16x8 b_lo = *(const bf16x8*)(lw_lo + lidx);
            acc[nt] = __builtin_amdgcn_mfma_f32_16x16x32_bf16(ah[ki], b_hi, acc[nt], 0, 0, 0);
            acc[nt] = __builtin_amdgcn_mfma_f32_16x16x32_bf16(al[ki], b_hi, acc[nt], 0, 0, 0);
            acc[nt] = __builtin_amdgcn_mfma_f32_16x16x32_bf16(ah[ki], b_lo, acc[nt], 0, 0, 0);
        }
    }

    // re-stage W cols 64-127 (W is L2-resident; x is not -- this trade wins)
    __syncthreads();
    for (int c = t; c < 1024; c += 256) {
        int n = c >> 4;
        int kk = (c & 15) * 8;
        *(bf16x8*)(lw_hi + n * LDK + kk) = *(const bf16x8*)(wt_hi + (64 + n) * F_IN + kk);
        *(bf16x8*)(lw_lo + n * LDK + kk) = *(const bf16x8*)(wt_lo + (64 + n) * F_IN + kk);
    }
    __syncthreads();

    // phase 2: MFMA cols 64-127 from the registered A-fragments
#pragma unroll
    for (int ki = 0; ki < 4; ++ki) {
        int koff = ki * 32 + q * 8;
#pragma unroll
        for (int nt = 0; nt < 4; ++nt) {
            int lidx = (nt * 16 + l15) * LDK + koff;
            bf16x8 b_hi = *(const bf16x8*)(lw_hi + lidx);
            bf16x8 b_lo = *(const bf16x8*)(lw_lo + lidx);
            acc[4 + nt] = __builtin_amdgcn_mfma_f32_16x16x32_bf16(ah[ki], b_hi, acc[4 + nt], 0, 0, 0);
            acc[4 + nt] = __builtin_amdgcn_mfma_f32_16x16x32_bf16(al[ki], b_hi, acc[4 + nt], 0, 0, 0);
            acc[4 + nt] = __builtin_amdgcn_mfma_f32_16x16x32_bf16(ah[ki], b_lo, acc[4 + nt], 0, 0, 0);
        }
    }

    if (!valid) return;

    int orow = strip * 16 + q * 4;
#pragma unroll
    for (int nt = 0; nt < 8; ++nt)
#pragma unroll
        for (int r = 0; r < 4; ++r)
            h_bf[(size_t)(orow + r) * HC + nt * 16 + l15] =
                (unsigned short)f2bf_rne(acc[nt][r]);

    // attention dots: all 4 heads; head hd uses acc[2hd], acc[2hd+1]
#pragma unroll
    for (int hd = 0; hd < 4; ++hd) {
        float as0 = att_src[hd * 32 + l15];
        float as1 = att_src[hd * 32 + 16 + l15];
        float ad0 = att_dst[hd * 32 + l15];
        float ad1 = att_dst[hd * 32 + 16 + l15];
#pragma unroll
        for (int r = 0; r < 4; ++r) {
            float ps = acc[2 * hd][r] * as0 + acc[2 * hd + 1][r] * as1;
            float pd = acc[2 * hd][r] * ad0 + acc[2 * hd + 1][r] * ad1;
#pragma unroll
            for (int off = 1; off < 16; off <<= 1) {
                ps += __shfl_xor(ps, off);
                pd += __shfl_xor(pd, off);
            }
            if (l15 == 0) {
                int row = orow + r;
                a_src[row * 4 + hd] = ps;
                a_dst[row * 4 + hd] = pd;
            }
        }
    }
}

// ---------------------------------------------------------------------------
// Kernel 3: bucketed multisplit pass 1.
__global__ __launch_bounds__(256) void bucket_scatter_kernel(
        const int* __restrict__ ei, const int* __restrict__ flag,
        int* __restrict__ bcur, unsigned* __restrict__ pairs) {
    __shared__ int lhist[NBKT];
    __shared__ int gbase[NBKT];
    int t = threadIdx.x;
    for (int i = t; i < NBKT; i += 256) lhist[i] = 0;
    __syncthreads();
    int is64 = *flag;
    int base = blockIdx.x * 4096;

    unsigned wrd[16];
    int meta[16];
#pragma unroll
    for (int it = 0; it < 16; ++it) {
        int e = base + it * 256 + t;
        if (e < NE) {
            int src = is64 ? ei[2 * e] : ei[e];
            int dst = is64 ? ei[2 * NE + 2 * e] : ei[NE + e];
            int b = dst >> 8;
            int r = atomicAdd(&lhist[b], 1);
            wrd[it] = (unsigned)src | ((unsigned)(dst & 255) << 17);
            meta[it] = b | (r << 9);
        } else {
            meta[it] = -1;
        }
    }
    __syncthreads();
    for (int i = t; i < NBKT; i += 256)
        gbase[i] = lhist[i] ? atomicAdd(&bcur[i], lhist[i]) : 0;
    __syncthreads();
#pragma unroll
    for (int it = 0; it < 16; ++it) {
        if (meta[it] >= 0) {
            int b = meta[it] & 511;
            int r = meta[it] >> 9;
            pairs[(size_t)b * BCAP + gbase[b] + r] = wrd[it];
        }
    }
}

// ---------------------------------------------------------------------------
// Kernel 4: bucket -> CSR + per-edge bf16 weights. Softmax denominators are
// now accumulated in the aggregation kernel (removes 4 LDS atomics/edge and
// the selfdata buffer entirely).
__global__ __launch_bounds__(256) void bucket_csr_kernel(
        const int* __restrict__ bcur, const unsigned* __restrict__ pairs,
        const float* __restrict__ a_src, const float* __restrict__ a_dst,
        int* __restrict__ deg, int* __restrict__ offsets,
        int* __restrict__ csr_src, unsigned* __restrict__ wal) {
    __shared__ unsigned lpairs[BCAP];   // 20 KB
    __shared__ int sd[256];
    __shared__ int cnt256[256];
    __shared__ int lcur[256];

    int b = blockIdx.x;
    int t = threadIdx.x;
    int node = (b << 8) + t;

    int partial = 0;
    for (int i = t; i < b; i += 256) partial += bcur[i];
    sd[t] = partial;
    __syncthreads();
    for (int off = 128; off > 0; off >>= 1) {
        if (t < off) sd[t] += sd[t + off];
        __syncthreads();
    }
    int bktbase = sd[0];
    __syncthreads();

    cnt256[t] = 0;
    __syncthreads();

    int cnt = bcur[b];
    const unsigned* __restrict__ bp = pairs + (size_t)b * BCAP;
    for (int i = t; i < cnt; i += 256) {
        unsigned w = bp[i];
        lpairs[i] = w;
        atomicAdd(&cnt256[w >> 17], 1);
    }
    __syncthreads();

    int v = cnt256[t];
    sd[t] = v;
    __syncthreads();
    for (int off = 1; off < 256; off <<= 1) {
        int u = (t >= off) ? sd[t - off] : 0;
        __syncthreads();
        sd[t] += u;
        __syncthreads();
    }
    int myoff = bktbase + sd[t] - v;
    if (node < NN) {
        deg[node] = v;
        offsets[node] = myoff;
    }
    lcur[t] = myoff;
    __syncthreads();

    for (int i = t; i < cnt; i += 256) {
        unsigned w = lpairs[i];
        int src = (int)(w & 0x1FFFFu);
        int dl = (int)(w >> 17);
        float4 as = ((const float4*)a_src)[src];
        float4 ad = ((const float4*)a_dst)[(b << 8) + dl];
        float e0 = as.x + ad.x; e0 = (e0 < 0.f) ? NEG_SLOPE * e0 : e0;
        float e1 = as.y + ad.y; e1 = (e1 < 0.f) ? NEG_SLOPE * e1 : e1;
        float e2 = as.z + ad.z; e2 = (e2 < 0.f) ? NEG_SLOPE * e2 : e2;
        float e3 = as.w + ad.w; e3 = (e3 < 0.f) ? NEG_SLOPE * e3 : e3;
        float w0 = __expf(e0), w1 = __expf(e1), w2 = __expf(e2), w3 = __expf(e3);
        int pos = atomicAdd(&lcur[dl], 1);
        csr_src[pos] = src;
        unsigned lo = (unsigned)(unsigned short)f2bf_rne(w0) |
                      ((unsigned)(unsigned short)f2bf_rne(w1) << 16);
        unsigned hi = (unsigned)(unsigned short)f2bf_rne(w2) |
                      ((unsigned)(unsigned short)f2bf_rne(w3) << 16);
        ((uint2*)wal)[pos] = make_uint2(lo, hi);
    }
}

// ---------------------------------------------------------------------------
// Kernel 5: per-node aggregation. One wave per dst; scalarized metadata,
// bf16 h gather, register accumulation. Softmax denominator accumulated
// in-register (wsum is identical across each 16-lane head group -> no
// cross-lane reduce needed). Unroll depth 8 for more gathers in flight.
__global__ __launch_bounds__(256) void gat_aggr_kernel(
        const int* __restrict__ offsets, const int* __restrict__ deg,
        const int* __restrict__ csr_src, const unsigned* __restrict__ wal,
        const float* __restrict__ a_src, const float* __restrict__ a_dst,
        const unsigned* __restrict__ h2, const float* __restrict__ bias,
        float* __restrict__ out) {
    int wid = (blockIdx.x * 256 + threadIdx.x) >> 6;
    int dst = __builtin_amdgcn_readfirstlane(wid);
    if (dst >= NN) return;
    int lane = threadIdx.x & 63;
    int hd = lane >> 4;
    unsigned hsel2 = (unsigned)(hd & 2);
    unsigned hsel1 = (unsigned)(hd & 1);

    int start = offsets[dst];
    int n = deg[dst];

    float accx = 0.f, accy = 0.f, wsum = 0.f;
    int j = 0;
    for (; j + 7 < n; j += 8) {
        int base = start + j;
        int s0 = csr_src[base + 0];
        int s1 = csr_src[base + 1];
        int s2 = csr_src[base + 2];
        int s3 = csr_src[base + 3];
        int s4 = csr_src[base + 4];
        int s5 = csr_src[base + 5];
        int s6 = csr_src[base + 6];
        int s7 = csr_src[base + 7];
        uint2 wv0 = ((const uint2*)wal)[base + 0];
        uint2 wv1 = ((const uint2*)wal)[base + 1];
        uint2 wv2 = ((const uint2*)wal)[base + 2];
        uint2 wv3 = ((const uint2*)wal)[base + 3];
        uint2 wv4 = ((const uint2*)wal)[base + 4];
        uint2 wv5 = ((const uint2*)wal)[base + 5];
        uint2 wv6 = ((const uint2*)wal)[base + 6];
        uint2 wv7 = ((const uint2*)wal)[base + 7];
        unsigned u0 = h2[(size_t)s0 * 64 + lane];
        unsigned u1 = h2[(size_t)s1 * 64 + lane];
        unsigned u2 = h2[(size_t)s2 * 64 + lane];
        unsigned u3 = h2[(size_t)s3 * 64 + lane];
        unsigned u4 = h2[(size_t)s4 * 64 + lane];
        unsigned u5 = h2[(size_t)s5 * 64 + lane];
        unsigned u6 = h2[(size_t)s6 * 64 + lane];
        unsigned u7 = h2[(size_t)s7 * 64 + lane];
        unsigned ws0 = hsel2 ? wv0.y : wv0.x;
        unsigned ws1 = hsel2 ? wv1.y : wv1.x;
        unsigned ws2 = hsel2 ? wv2.y : wv2.x;
        unsigned ws3 = hsel2 ? wv3.y : wv3.x;
        unsigned ws4 = hsel2 ? wv4.y : wv4.x;
        unsigned ws5 = hsel2 ? wv5.y : wv5.x;
        unsigned ws6 = hsel2 ? wv6.y : wv6.x;
        unsigned ws7 = hsel2 ? wv7.y : wv7.x;
        float w0 = __uint_as_float(hsel1 ? (ws0 & 0xFFFF0000u) : (ws0 << 16));
        float w1 = __uint_as_float(hsel1 ? (ws1 & 0xFFFF0000u) : (ws1 << 16));
        float w2 = __uint_as_float(hsel1 ? (ws2 & 0xFFFF0000u) : (ws2 << 16));
        float w3 = __uint_as_float(hsel1 ? (ws3 & 0xFFFF0000u) : (ws3 << 16));
        float w4 = __uint_as_float(hsel1 ? (ws4 & 0xFFFF0000u) : (ws4 << 16));
        float w5 = __uint_as_float(hsel1 ? (ws5 & 0xFFFF0000u) : (ws5 << 16));
        float w6 = __uint_as_float(hsel1 ? (ws6 & 0xFFFF0000u) : (ws6 << 16));
        float w7 = __uint_as_float(hsel1 ? (ws7 & 0xFFFF0000u) : (ws7 << 16));
        wsum += ((w0 + w1) + (w2 + w3)) + ((w4 + w5) + (w6 + w7));
        accx += w0 * __uint_as_float(u0 << 16);
        accy += w0 * __uint_as_float(u0 & 0xFFFF0000u);
        accx += w1 * __uint_as_float(u1 << 16);
        accy += w1 * __uint_as_float(u1 & 0xFFFF0000u);
        accx += w2 * __uint_as_float(u2 << 16);
        accy += w2 * __uint_as_float(u2 & 0xFFFF0000u);
        accx += w3 * __uint_as_float(u3 << 16);
        accy += w3 * __uint_as_float(u3 & 0xFFFF0000u);
        accx += w4 * __uint_as_float(u4 << 16);
        accy += w4 * __uint_as_float(u4 & 0xFFFF0000u);
        accx += w5 * __uint_as_float(u5 << 16);
        accy += w5 * __uint_as_float(u5 & 0xFFFF0000u);
        accx += w6 * __uint_as_float(u6 << 16);
        accy += w6 * __uint_as_float(u6 & 0xFFFF0000u);
        accx += w7 * __uint_as_float(u7 << 16);
        accy += w7 * __uint_as_float(u7 & 0xFFFF0000u);
    }
    for (; j + 3 < n; j += 4) {
        int base = start + j;
        int s0 = csr_src[base + 0];
        int s1 = csr_src[base + 1];
        int s2 = csr_src[base + 2];
        int s3 = csr_src[base + 3];
        uint2 wv0 = ((const uint2*)wal)[base + 0];
        uint2 wv1 = ((const uint2*)wal)[base + 1];
        uint2 wv2 = ((const uint2*)wal)[base + 2];
        uint2 wv3 = ((const uint2*)wal)[base + 3];
        unsigned u0 = h2[(size_t)s0 * 64 + lane];
        unsigned u1 = h2[(size_t)s1 * 64 + lane];
        unsigned u2 = h2[(size_t)s2 * 64 + lane];
        unsigned u3 = h2[(size_t)s3 * 64 + lane];
        unsigned ws0 = hsel2 ? wv0.y : wv0.x;
        unsigned ws1 = hsel2 ? wv1.y : wv1.x;
        unsigned ws2 = hsel2 ? wv2.y : wv2.x;
        unsigned ws3 = hsel2 ? wv3.y : wv3.x;
        float w0 = __uint_as_float(hsel1 ? (ws0 & 0xFFFF0000u) : (ws0 << 16));
        float w1 = __uint_as_float(hsel1 ? (ws1 & 0xFFFF0000u) : (ws1 << 16));
        float w2 = __uint_as_float(hsel1 ? (ws2 & 0xFFFF0000u) : (ws2 << 16));
        float w3 = __uint_as_float(hsel1 ? (ws3 & 0xFFFF0000u) : (ws3 << 16));
        wsum += (w0 + w1) + (w2 + w3);
        accx += w0 * __uint_as_float(u0 << 16);
        accy += w0 * __uint_as_float(u0 & 0xFFFF0000u);
        accx += w1 * __uint_as_float(u1 << 16);
        accy += w1 * __uint_as_float(u1 & 0xFFFF0000u);
        accx += w2 * __uint_as_float(u2 << 16);
        accy += w2 * __uint_as_float(u2 & 0xFFFF0000u);
        accx += w3 * __uint_as_float(u3 << 16);
        accy += w3 * __uint_as_float(u3 & 0xFFFF0000u);
    }
    for (; j < n; ++j) {
        int base = start + j;
        int s0 = csr_src[base];
        uint2 wv0 = ((const uint2*)wal)[base];
        unsigned u0 = h2[(size_t)s0 * 64 + lane];
        unsigned ws0 = hsel2 ? wv0.y : wv0.x;
        float w0 = __uint_as_float(hsel1 ? (ws0 & 0xFFFF0000u) : (ws0 << 16));
        wsum += w0;
        accx += w0 * __uint_as_float(u0 << 16);
        accy += w0 * __uint_as_float(u0 & 0xFFFF0000u);
    }

    // self-loop weight + softmax normalization (per head; uniform across the
    // 16 lanes of each head group)
    float e = a_src[dst * 4 + hd] + a_dst[dst * 4 + hd];
    e = (e < 0.f) ? NEG_SLOPE * e : e;
    float sf = __expf(e);
    float inv = 1.f / (wsum + sf + 1e-16f);

    unsigned us = h2[(size_t)dst * 64 + lane];
    float2 b2 = ((const float2*)bias)[lane];
    float ox = tanhf((accx + sf * __uint_as_float(us << 16)) * inv + b2.x);
    float oy = tanhf((accy + sf * __uint_as_float(us & 0xFFFF0000u)) * inv + b2.y);
    ((float2*)out)[(size_t)dst * 64 + lane] = make_float2(ox, oy);
}

// ---------------------------------------------------------------------------
extern "C" void kernel_launch(void* const* d_in, const int* in_sizes, int n_in,
                              void* d_out, int out_size, void* d_ws, size_t ws_size,
                              hipStream_t stream) {
    const float* x       = (const float*)d_in[0];
    const int*   ei      = (const int*)  d_in[1];
    const float* W       = (const float*)d_in[2];
    const float* att_src = (const float*)d_in[3];
    const float* att_dst = (const float*)d_in[4];
    const float* bias    = (const float*)d_in[5];
    float* out = (float*)d_out;

    unsigned short* h_bf = (unsigned short*)d_ws;            // NN*128 bf16 (25.6 MB)
    float* a_src = (float*)(h_bf + (size_t)NN * HC);         // NN*4
    float* a_dst = a_src + (size_t)NN * HEADS;               // NN*4
    short* wt_hi = (short*)(a_dst + (size_t)NN * HEADS);     // 16384
    short* wt_lo = wt_hi + F_IN * HC;                        // 16384
    int* flag    = (int*)(wt_lo + F_IN * HC);
    int* bcur    = flag + 4;                 // NBKT
    int* deg     = bcur + NBKT + 1;          // NN
    int* offsets = deg + NN;                 // NN
    int* csr_src = offsets + NN;             // NE (6.4 MB)
    unsigned* wal = (unsigned*)(csr_src + NE);               // NE*2 (12.8 MB)
    unsigned* pairs = (unsigned*)(wal + (size_t)NE * 2);     // NBKT*BCAP (8 MB)

    hipLaunchKernelGGL(prep_kernel, dim3(64), dim3(256), 0, stream,
                       W, wt_hi, wt_lo, ei, flag, bcur);

    hipLaunchKernelGGL(bucket_scatter_kernel, dim3((NE + 4095) / 4096), dim3(256), 0, stream,
                       ei, flag, bcur, pairs);

    // 1563 row-blocks (64 rows each, last partial), full 128-col width
    hipLaunchKernelGGL(mfma_gemm_kernel, dim3(1563), dim3(256), 0, stream,
                       x, wt_hi, wt_lo, att_src, att_dst, h_bf, a_src, a_dst);

    hipLaunchKernelGGL(bucket_csr_kernel, dim3(NBKT), dim3(256), 0, stream,
                       bcur, pairs, a_src, a_dst, deg, offsets, csr_src, wal);

    hipLaunchKernelGGL(gat_aggr_kernel, dim3(NN * 64 / 256), dim3(256), 0, stream,
                       offsets, deg, csr_src, wal, a_src, a_dst,
                       (const unsigned*)h_bf, bias, out);
}